// Round 2
// baseline (4381.752 us; speedup 1.0000x reference)
//
#include <hip/hip_runtime.h>
#include <math.h>

#define NB    4096
#define NH    128
#define NKIN  8
#define NKOUT 4
#define NTP   64
#define NL    128
#define NBT   8            // batch columns per block (half-tile -> 2 blocks/CU)
#define BKIN  (NB*NKIN)
#define LOG2E 1.44269504088896340736f

// lgkm-only barrier: orders LDS ops across the block WITHOUT draining in-flight
// global loads. Safe: loops have no cross-thread global dependencies.
#define BAR() asm volatile("s_waitcnt lgkmcnt(0)\n\ts_barrier" ::: "memory")

typedef __attribute__((ext_vector_type(8))) short short8;
typedef __attribute__((ext_vector_type(4))) float f32x4;

#if __has_builtin(__builtin_amdgcn_exp2f)
#define EXP2F __builtin_amdgcn_exp2f
#else
#define EXP2F exp2f
#endif

__device__ __forceinline__ short f2bf(float f) {
    union { float f; unsigned u; } v; v.f = f;
    unsigned u = v.u;
    return (short)((u + 0x7fffu + ((u >> 16) & 1u)) >> 16);
}
__device__ __forceinline__ unsigned pkbf2(float a, float b) {
#if __has_builtin(__builtin_amdgcn_cvt_pk_bf16_f32)
    auto p = __builtin_amdgcn_cvt_pk_bf16_f32(a, b);
    unsigned q; __builtin_memcpy(&q, &p, 4); return q;
#else
    union { float f; unsigned u; } x, y; x.f = a; y.f = b;
    unsigned ua = (x.u + 0x7fffu + ((x.u >> 16) & 1u)) >> 16;
    unsigned ub = (y.u + 0x7fffu + ((y.u >> 16) & 1u)) & 0xffff0000u;
    return ua | ub;
#endif
}
__device__ __forceinline__ void st4(short* dst, const f32x4& v) {
    uint2 q; q.x = pkbf2(v[0], v[1]); q.y = pkbf2(v[2], v[3]);
    *(uint2*)dst = q;
}
__device__ __forceinline__ f32x4 exp24(f32x4 a) {
    f32x4 r;
    #pragma unroll
    for (int i = 0; i < 4; ++i) r[i] = EXP2F(a[i]);
    return r;
}
// tanh of one vector: denominators paired (0,1),(2,3) -> 2 rcp instead of 4.
// tanh(x) computed as 1 - 2/(e^{2x}+1); input is pre-scaled by 2*LOG2E.
__device__ __forceinline__ f32x4 tanh1(const f32x4& a) {
    f32x4 E = exp24(a) + 1.0f, t;
    #pragma unroll
    for (int i = 0; i < 4; i += 2) {
        float R = __builtin_amdgcn_rcpf(E[i]*E[i+1]);
        t[i]   = 1.0f - 2.0f*(R*E[i+1]);
        t[i+1] = 1.0f - 2.0f*(R*E[i]);
    }
    return t;
}
// tanh of two vectors: pair elementwise across the two -> 4 rcp instead of 8.
__device__ __forceinline__ void tanh2(const f32x4& a, const f32x4& b, f32x4& ta, f32x4& tb) {
    f32x4 Ea = exp24(a) + 1.0f, Eb = exp24(b) + 1.0f;
    #pragma unroll
    for (int i = 0; i < 4; ++i) {
        float R = __builtin_amdgcn_rcpf(Ea[i]*Eb[i]);
        ta[i] = 1.0f - 2.0f*(R*Eb[i]);
        tb[i] = 1.0f - 2.0f*(R*Ea[i]);
    }
}

// ---------------- prep: W1/W2 as A-operand fragments (bf16, W1 pre-scaled) ----
__global__ void prep_frags(const float* __restrict__ W1, const float* __restrict__ W2,
                           short* __restrict__ w1f, short* __restrict__ w2f)
{
    int tid0 = blockIdx.x*256 + threadIdx.x;
    for (int idx = tid0; idx < 16*4*64*8; idx += 8*256) {
        int j = idx & 7, lane = (idx >> 3) & 63, kc = (idx >> 9) & 3, t = idx >> 11;
        int row = t*16 + (lane & 15);
        int k   = kc*32 + (lane >> 4)*8 + j;
        w1f[idx] = f2bf(2.0f*LOG2E*W1[row*NH + k]);
    }
    for (int idx = tid0; idx < 8*64*8; idx += 8*256) {
        int j = idx & 7, lane = (idx >> 3) & 63, kc = idx >> 9;
        int m = lane & 15;
        int k = kc*32 + (lane >> 4)*8 + j;
        w2f[idx] = (m < NKOUT) ? f2bf(W2[m*2*NH + k]) : (short)0;
    }
}

// ---------------- fused kernel helpers ----------------
__device__ __forceinline__ void ld4(const short* bp, short8 (&bf)[4]) {
    #pragma unroll
    for (int kc = 0; kc < 4; ++kc) bf[kc] = *(const short8*)(bp + kc*32);
}
__device__ __forceinline__ void gemmR(const short8 (&bf)[4], const short8 (&A)[3][4],
                                      f32x4 (&acc)[3]) {
    #pragma unroll
    for (int kc = 0; kc < 4; ++kc)
        #pragma unroll
        for (int g = 0; g < 3; ++g)
            acc[g] = __builtin_amdgcn_mfma_f32_16x16x32_bf16(A[g][kc], bf[kc], acc[g], 0, 0, 0);
}
__device__ __forceinline__ void gemmB(const short* bp, const short8 (&A)[3][4], f32x4 (&acc)[3]) {
    short8 bf[4]; ld4(bp, bf); gemmR(bf, A, acc);
}
// r-gate scaled -LOG2E (rg = sigmoid), z-gate scaled +LOG2E (zc = 1-z),
// n-gate scaled 2*LOG2E (tanh). K = (1-z)*(n - y).
// Reciprocal pairing: r/z denominators are independent -> 1 rcp for both.
__device__ __forceinline__ void gateK(const f32x4 (&gi)[3], const f32x4 (&gh)[3],
                                      const f32x4& yin, f32x4& K)
{
    f32x4 Ea = exp24(gi[0] + gh[0]) + 1.0f;   // r denom
    f32x4 Eb = exp24(gi[1] + gh[1]) + 1.0f;   // z denom
    f32x4 rg, zc;
    #pragma unroll
    for (int i = 0; i < 4; ++i) {
        float R = __builtin_amdgcn_rcpf(Ea[i]*Eb[i]);
        rg[i] = R*Eb[i];
        zc[i] = R*Ea[i];
    }
    f32x4 Ec = exp24(gi[2] + rg*gh[2]) + 1.0f;
    f32x4 tg;
    #pragma unroll
    for (int i = 0; i < 4; i += 2) {
        float R = __builtin_amdgcn_rcpf(Ec[i]*Ec[i+1]);
        tg[i]   = 1.0f - 2.0f*(R*Ec[i+1]);
        tg[i+1] = 1.0f - 2.0f*(R*Ec[i]);
    }
    K = zc*(tg - yin);
}

// 2 blocks/CU: grid 512, 8 real batch cols per block (MFMA cols 8-15 carry
// finite/contained garbage, never stored). launch_bounds(512,4) = 16 waves/CU
// pins VGPR <= 128 so both blocks co-reside.
__global__ void __launch_bounds__(512, 4)
fused_kernel(const float* __restrict__ pre_x, const float* __restrict__ pre_y,
             const float* __restrict__ fx,
             const float* __restrict__ W_ih, const float* __restrict__ W_hh,
             const float* __restrict__ b_ih, const float* __restrict__ b_hh,
             const float* __restrict__ W_e,  const float* __restrict__ b_e,
             const float* __restrict__ Wc_ih,const float* __restrict__ Wc_hh,
             const float* __restrict__ bc_ih,const float* __restrict__ bc_hh,
             float* __restrict__ UM,         const short* __restrict__ w1f,
             const short* __restrict__ w2f,  float* __restrict__ out)
{
    __shared__ __align__(16) short yTa[16*136];   // enc ping / RK4 y
    __shared__ __align__(16) short yTb[16*136];   // enc pong / RK4 ye1, ye3
    __shared__ __align__(16) short E1 [16*136];   // spline cp (prologue) / ye2
    __shared__ __align__(16) short xmT[16*136];
    __shared__ __align__(16) short x1T[16*136];
    __shared__ __align__(16) short UMb[16*40];
    __shared__ __align__(16) short U1b[16*40];
    __shared__ __align__(16) short oT [16*264];
    __shared__ __align__(16) short w2S[8*64*8];   // W2 A-frags resident in LDS (8 KB)

    const int tid  = threadIdx.x;
    const int w    = tid >> 6;
    const int lane = tid & 63;
    const int quad = lane >> 4;
    const int m    = lane & 15;
    const int hq   = w*16 + quad*4;
    const int b0   = blockIdx.x * NBT;
    const f32x4 z4 = {0.f, 0.f, 0.f, 0.f};
    const float scg[3] = {-LOG2E, LOG2E, 2.0f*LOG2E};   // r, z(flipped), n

    for (int i = tid; i < 16*136; i += 512) yTa[i] = 0;
    for (int i = tid; i < 16*40;  i += 512) { UMb[i] = 0; U1b[i] = 0; }
    ((short8*)w2S)[tid & 511] = ((const short8*)w2f)[tid & 511];   // 512 frags, 1/thread

    f32x4 y = z4;

    // ================= encoder GRU: 1 fast barrier/step =================
    {
        short8 Ehh[3][4];
        #pragma unroll
        for (int g = 0; g < 3; ++g)
            #pragma unroll
            for (int c = 0; c < 4; ++c) {
                const float* ph = W_hh + (size_t)(g*NH + w*16 + m)*NH + c*32 + quad*8;
                short8 fh;
                #pragma unroll
                for (int j = 0; j < 8; ++j) fh[j] = f2bf(scg[g]*ph[j]);
                Ehh[g][c] = fh;
            }
        short8 Eih[3];
        #pragma unroll
        for (int g = 0; g < 3; ++g) {
            short8 f1;
            #pragma unroll
            for (int j = 0; j < 8; ++j) {
                int k = quad*8 + j;
                f1[j] = (k < 12) ? f2bf(scg[g]*W_ih[(size_t)(g*NH + w*16 + m)*12 + k]) : (short)0;
            }
            Eih[g] = f1;
        }
        f32x4 erz4, ezz4, egn4, ein4;
        #pragma unroll
        for (int r = 0; r < 4; ++r) {
            int h = hq + r;
            erz4[r] = -LOG2E*(b_ih[h]      + b_hh[h]);
            ezz4[r] =  LOG2E*(b_ih[NH + h] + b_hh[NH + h]);
            egn4[r] = 2.0f*LOG2E*b_hh[2*NH + h];
            ein4[r] = 2.0f*LOG2E*b_ih[2*NH + h];
        }
        // staging: wave w stages batch col w; lanes 0-11 carry the 12 inputs
        const int eb = w, ek = lane;
        const bool estg = (lane < 12);
        float encv = 0.f;
        if (estg) {
            float e0 = (ek < NKIN) ? pre_x[((size_t)0*NB + b0 + eb)*NKIN + ek]
                                   : pre_y[((size_t)0*NB + b0 + eb)*NKOUT + (ek - NKIN)];
            UMb[eb*40 + ek] = f2bf(e0);
            encv = (ek < NKIN) ? pre_x[((size_t)1*NB + b0 + eb)*NKIN + ek]
                               : pre_y[((size_t)1*NB + b0 + eb)*NKOUT + (ek - NKIN)];
        }
        BAR();
        for (int t = 0; t < NTP; ++t) {
            float evn = 0.f;
            if (estg) {
                int tn = (t + 2 < NTP) ? t + 2 : NTP - 1;
                evn = (ek < NKIN) ? pre_x[((size_t)tn*NB + b0 + eb)*NKIN + ek]
                                  : pre_y[((size_t)tn*NB + b0 + eb)*NKOUT + (ek - NKIN)];
            }
            const short* bin_buf  = (t & 1) ? U1b : UMb;
            short*       bout_buf = (t & 1) ? UMb : U1b;
            const short* sin_buf  = (t & 1) ? yTb : yTa;
            short*       sout_buf = (t & 1) ? yTa : yTb;
            f32x4 gi[3] = {z4, z4, ein4};
            {
                short8 b = *(const short8*)(bin_buf + m*40 + quad*8);
                #pragma unroll
                for (int g = 0; g < 3; ++g)
                    gi[g] = __builtin_amdgcn_mfma_f32_16x16x32_bf16(Eih[g], b, gi[g], 0, 0, 0);
            }
            f32x4 gh[3] = {erz4, ezz4, egn4};
            gemmB(sin_buf + m*136 + quad*8, Ehh, gh);
            f32x4 K;
            gateK(gi, gh, y, K);
            y += K;
            st4(sout_buf + m*136 + hq, y);
            if (estg) { bout_buf[eb*40 + ek] = f2bf(encv); encv = evn; }
            BAR();
        }
    }
    // y(0) in regs; final enc state in yTa (t=63 odd wrote yTa)

    // ---- persistent RK4 A-frags ----
    short8 Ahh[3][4], Aih[3][4];
    #pragma unroll
    for (int g = 0; g < 3; ++g)
        #pragma unroll
        for (int c = 0; c < 4; ++c) {
            const float* ph = Wc_hh + (size_t)(g*NH + w*16 + m)*NH + c*32 + quad*8;
            const float* pi = Wc_ih + (size_t)(g*NH + w*16 + m)*NH + c*32 + quad*8;
            short8 fh, fi;
            #pragma unroll
            for (int j = 0; j < 8; ++j) { fh[j] = f2bf(scg[g]*ph[j]); fi[j] = f2bf(scg[g]*pi[j]); }
            Ahh[g][c] = fh; Aih[g][c] = fi;
        }
    short8 Aexp;
    #pragma unroll
    for (int j = 0; j < 8; ++j) {
        int k = quad*8 + j;
        Aexp[j] = (k < NKIN) ? f2bf(2.0f*LOG2E*W_e[(w*16 + m)*NKIN + k]) : (short)0;
    }
    short8 A1f[2][4];
    #pragma unroll
    for (int kc = 0; kc < 4; ++kc) {
        A1f[0][kc] = *(const short8*)(w1f + (size_t)(((w    )*4 + kc)*64 + lane)*8);
        A1f[1][kc] = *(const short8*)(w1f + (size_t)(((w + 8)*4 + kc)*64 + lane)*8);
    }
    f32x4 brz4, bzz4, bgn4, bin4, be4;
    #pragma unroll
    for (int r = 0; r < 4; ++r) {
        int h = hq + r;
        brz4[r] = -LOG2E*(bc_ih[h]      + bc_hh[h]);
        bzz4[r] =  LOG2E*(bc_ih[NH + h] + bc_hh[NH + h]);
        bgn4[r] = 2.0f*LOG2E*bc_hh[2*NH + h];
        bin4[r] = 2.0f*LOG2E*bc_ih[2*NH + h];
        be4[r]  = 2.0f*LOG2E*b_e[h];
    }

    // ================= in-kernel spline (Thomas, reversed elimination) =================
    // wave w owns batch col w; lanes 0-7 own the 8 input channels
    const bool stg = (lane < 8);
    const int sb = w, sk = lane;
    const size_t scol = (size_t)(b0 + sb)*NKIN + sk;   // only valid for stg lanes
    float* cpS = (float*)E1;
    float prex_last = 0.f;
    if (stg) prex_last = pre_x[(size_t)(NTP-1)*BKIN + scol];
    if (stg) {
        const float r6 = 6.0f/(0.1f*0.1f);
        float c = 0.f, d = 0.f;
        float yp = fx[(size_t)127*BKIN + scol];
        float y0 = fx[(size_t)126*BKIN + scol];
        float ym = fx[(size_t)125*BKIN + scol];
        #pragma unroll 4
        for (int j = 127; j >= 1; --j) {
            float r = r6*(ym - 2.f*y0 + yp);
            c = __builtin_amdgcn_rcpf(4.f - c);
            d = (r - d)*c;
            UM[(size_t)j*BKIN + scol] = d;
            if (tid == 0) cpS[128 - j] = c;
            yp = y0; y0 = ym;
            ym = (j >= 3) ? fx[(size_t)(j-3)*BKIN + scol] : prex_last;
        }
    }
    __syncthreads();   // FULL: same-thread global RAW on UM
    if (stg) {
        const float KK = 0.01f/16.0f;
        float Mp = 0.f;
        float y0 = prex_last;
        float y1 = fx[scol];
        #pragma unroll 4
        for (int j = 1; j <= 127; ++j) {
            float dj = UM[(size_t)j*BKIN + scol];
            float e  = cpS[128 - j];
            float Mj = dj - e*Mp;
            UM[(size_t)(j-1)*BKIN + scol] = 0.5f*(y0 + y1) - KK*(Mp + Mj);
            Mp = Mj; y0 = y1;
            y1 = fx[(size_t)j*BKIN + scol];
        }
        UM[(size_t)127*BKIN + scol] = 0.5f*(y0 + y1) - KK*Mp;
    }
    __syncthreads();   // FULL: UM writes drained; E1 free again

    // ================= RK4 prologue =================
    if (stg) {
        UMb[sb*40 + 8 + (lane & 3)] = 0;
        U1b[sb*40 + 8 + (lane & 3)] = 0;
        UMb[sb*40 + sk] = f2bf(prex_last);
    }
    BAR();
    {   // x0 = tanh-expand(u0_start) -> xmT
        short8 b = *(const short8*)(UMb + m*40 + quad*8);
        f32x4 c0 = be4;
        c0 = __builtin_amdgcn_mfma_f32_16x16x32_bf16(Aexp, b, c0, 0, 0, 0);
        f32x4 xv = tanh1(c0);
        st4(xmT + m*136 + hq, xv);
    }
    BAR();
    f32x4 gi0[3] = {z4, z4, bin4};
    gemmB(xmT + m*136 + quad*8, Aih, gi0);
    if (stg) { UMb[sb*40 + sk] = f2bf(UM[scol]); U1b[sb*40 + sk] = f2bf(fx[scol]); }
    BAR();
    {   // expand u(0) -> xmT, x1T
        short8 bm = *(const short8*)(UMb + m*40 + quad*8);
        short8 b1 = *(const short8*)(U1b + m*40 + quad*8);
        f32x4 cm = be4, c1 = be4;
        cm = __builtin_amdgcn_mfma_f32_16x16x32_bf16(Aexp, bm, cm, 0, 0, 0);
        c1 = __builtin_amdgcn_mfma_f32_16x16x32_bf16(Aexp, b1, c1, 0, 0, 0);
        f32x4 xm, x1;
        tanh2(cm, c1, xm, x1);
        st4(xmT + m*136 + hq, xm);
        st4(x1T + m*136 + hq, x1);
    }
    float fxv = 0.f, umv = 0.f;
    if (stg) { fxv = fx[(size_t)BKIN + scol]; umv = UM[(size_t)BKIN + scol]; }  // u(1)
    BAR();
    f32x4 gim[3] = {z4, z4, bin4}, gi1[3] = {z4, z4, bin4};
    gemmB(xmT + m*136 + quad*8, Aih, gim);
    gemmB(x1T + m*136 + quad*8, Aih, gi1);

    // ================= RK4 loop: 4 fast barriers/step =================
    // P1 = k1 + head1(st-1) | P2 = k2 + stage2(st-1) + staging u(st+1)
    // P3 = k3 + expand(st+1) | P4 = k4 + y-upd + gim/gi1(st+1) + prefetch u(st+2)
    for (int st = 0; st < NL; ++st) {
        // ---- P1: k1 + head1(st-1) (shared yTa read) ----
        short8 byf[4];
        ld4(yTa + m*136 + quad*8, byf);
        f32x4 gh[3] = {brz4, bzz4, bgn4};
        gemmR(byf, Ahh, gh);
        if (st > 0) {
            f32x4 o0 = z4, o1 = z4;
            #pragma unroll
            for (int kc = 0; kc < 4; ++kc) {
                o0 = __builtin_amdgcn_mfma_f32_16x16x32_bf16(A1f[0][kc], byf[kc], o0, 0, 0, 0);
                o1 = __builtin_amdgcn_mfma_f32_16x16x32_bf16(A1f[1][kc], byf[kc], o1, 0, 0, 0);
            }
            f32x4 t0, t1;
            tanh2(o0, o1, t0, t1);
            st4(oT + m*264 + w*16     + quad*4, t0);
            st4(oT + m*264 + (w+8)*16 + quad*4, t1);
        }
        f32x4 K, Ks, ye;
        gateK(gi0, gh, y, K);
        Ks = K; ye = y + 0.5f*K;
        st4(yTb + m*136 + hq, ye);
        BAR();                                                  // B1
        // ---- P2: k2 + stage2(st-1) + staging u(st+1) ----
        if (stg) { UMb[sb*40 + sk] = f2bf(umv); U1b[sb*40 + sk] = f2bf(fxv); }
        gh[0] = brz4; gh[1] = bzz4; gh[2] = bgn4;
        gemmB(yTb + m*136 + quad*8, Ahh, gh);
        if (st > 0 && w == ((st-1) & 7)) {
            f32x4 oc = z4;
            #pragma unroll
            for (int kc = 0; kc < 8; ++kc) {
                short8 a2 = *(const short8*)(w2S + (kc*64 + lane)*8);
                short8 b  = *(const short8*)(oT + m*264 + kc*32 + quad*8);
                oc = __builtin_amdgcn_mfma_f32_16x16x32_bf16(a2, b, oc, 0, 0, 0);
            }
            if (quad == 0 && m < NBT)
                *(f32x4*)(out + ((size_t)(st-1)*NB + b0 + m)*NKOUT) = oc;
        }
        gateK(gim, gh, ye, K);
        Ks += 2.0f*K; ye = y + 0.5f*K;
        st4(E1 + m*136 + hq, ye);
        BAR();                                                  // B2
        // ---- P3: k3 + expand(st+1) ----
        gh[0] = brz4; gh[1] = bzz4; gh[2] = bgn4;
        gemmB(E1 + m*136 + quad*8, Ahh, gh);
        {
            short8 bm = *(const short8*)(UMb + m*40 + quad*8);
            short8 b1 = *(const short8*)(U1b + m*40 + quad*8);
            f32x4 cm = be4, c1 = be4;
            cm = __builtin_amdgcn_mfma_f32_16x16x32_bf16(Aexp, bm, cm, 0, 0, 0);
            c1 = __builtin_amdgcn_mfma_f32_16x16x32_bf16(Aexp, b1, c1, 0, 0, 0);
            f32x4 xm, x1;
            tanh2(cm, c1, xm, x1);
            st4(xmT + m*136 + hq, xm);
            st4(x1T + m*136 + hq, x1);
        }
        gateK(gim, gh, ye, K);
        Ks += 2.0f*K; ye = y + K;
        st4(yTb + m*136 + hq, ye);
        BAR();                                                  // B3
        // ---- P4: k4 + y update + gim/gi1(st+1) + prefetch u(st+2) ----
        if (stg) {
            int sn = (st + 2 < NL) ? st + 2 : NL - 1;
            fxv = fx[(size_t)sn*BKIN + scol];
            umv = UM[(size_t)sn*BKIN + scol];
        }
        gh[0] = brz4; gh[1] = bzz4; gh[2] = bgn4;
        gemmB(yTb + m*136 + quad*8, Ahh, gh);
        gateK(gi1, gh, ye, K);
        y += (1.0f/6.0f)*(Ks + K);
        st4(yTa + m*136 + hq, y);
        gi0[0] = gi1[0]; gi0[1] = gi1[1]; gi0[2] = gi1[2];
        gim[0] = z4; gim[1] = z4; gim[2] = bin4;
        gi1[0] = z4; gi1[1] = z4; gi1[2] = bin4;
        gemmB(xmT + m*136 + quad*8, Aih, gim);
        gemmB(x1T + m*136 + quad*8, Aih, gi1);
        BAR();                                                  // B4
    }

    // ================= epilogue: head + stage2 for out[127] =================
    {
        short8 byf[4];
        ld4(yTa + m*136 + quad*8, byf);
        f32x4 o0 = z4, o1 = z4;
        #pragma unroll
        for (int kc = 0; kc < 4; ++kc) {
            o0 = __builtin_amdgcn_mfma_f32_16x16x32_bf16(A1f[0][kc], byf[kc], o0, 0, 0, 0);
            o1 = __builtin_amdgcn_mfma_f32_16x16x32_bf16(A1f[1][kc], byf[kc], o1, 0, 0, 0);
        }
        f32x4 t0, t1;
        tanh2(o0, o1, t0, t1);
        st4(oT + m*264 + w*16     + quad*4, t0);
        st4(oT + m*264 + (w+8)*16 + quad*4, t1);
        BAR();
        if (w == 7) {
            f32x4 oc = z4;
            #pragma unroll
            for (int kc = 0; kc < 8; ++kc) {
                short8 a2 = *(const short8*)(w2S + (kc*64 + lane)*8);
                short8 b  = *(const short8*)(oT + m*264 + kc*32 + quad*8);
                oc = __builtin_amdgcn_mfma_f32_16x16x32_bf16(a2, b, oc, 0, 0, 0);
            }
            if (quad == 0 && m < NBT)
                *(f32x4*)(out + ((size_t)(NL-1)*NB + b0 + m)*NKOUT) = oc;
        }
    }
}

extern "C" void kernel_launch(void* const* d_in, const int* in_sizes, int n_in,
                              void* d_out, int out_size, void* d_ws, size_t ws_size,
                              hipStream_t stream)
{
    const float* pre_x = (const float*)d_in[0];
    const float* pre_y = (const float*)d_in[1];
    const float* fx    = (const float*)d_in[2];
    const float* W_ih  = (const float*)d_in[3];
    const float* W_hh  = (const float*)d_in[4];
    const float* b_ih  = (const float*)d_in[5];
    const float* b_hh  = (const float*)d_in[6];
    const float* W_e   = (const float*)d_in[7];
    const float* b_e   = (const float*)d_in[8];
    const float* Wc_ih = (const float*)d_in[9];
    const float* Wc_hh = (const float*)d_in[10];
    const float* bc_ih = (const float*)d_in[11];
    const float* bc_hh = (const float*)d_in[12];
    const float* W1    = (const float*)d_in[13];
    const float* W2    = (const float*)d_in[14];
    float* out = (float*)d_out;

    float* UM  = (float*)d_ws;                                  // 128*4096*8 fp32 = 16.78 MB
    short* w1f = (short*)((char*)d_ws + (size_t)NL*NB*NKIN*4);  // 32768 shorts
    short* w2f = w1f + 16*4*64*8;                               // 4096 shorts

    prep_frags<<<dim3(8), dim3(256), 0, stream>>>(W1, W2, w1f, w2f);
    fused_kernel<<<dim3(NB/NBT), dim3(512), 0, stream>>>(
        pre_x, pre_y, fx, W_ih, W_hh, b_ih, b_hh, W_e, b_e,
        Wc_ih, Wc_hh, bc_ih, bc_hh, UM, w1f, w2f, out);
}

// Round 3
// 1283.691 us; speedup vs baseline: 3.4134x; 3.4134x over previous
//
#include <hip/hip_runtime.h>
#include <math.h>

#define NB    4096
#define NH    128
#define NKIN  8
#define NKOUT 4
#define NTP   64
#define NL    128
#define NBT   8            // batch columns per block (half-tile -> 2 blocks/CU)
#define BKIN  (NB*NKIN)
#define LOG2E 1.44269504088896340736f

// lgkm-only barrier: orders LDS ops across the block WITHOUT draining in-flight
// global loads. Safe: loops have no cross-thread global dependencies.
#define BAR() asm volatile("s_waitcnt lgkmcnt(0)\n\ts_barrier" ::: "memory")

typedef __attribute__((ext_vector_type(8))) short short8;
typedef __attribute__((ext_vector_type(4))) float f32x4;

#if __has_builtin(__builtin_amdgcn_exp2f)
#define EXP2F __builtin_amdgcn_exp2f
#else
#define EXP2F exp2f
#endif

__device__ __forceinline__ short f2bf(float f) {
    union { float f; unsigned u; } v; v.f = f;
    unsigned u = v.u;
    return (short)((u + 0x7fffu + ((u >> 16) & 1u)) >> 16);
}
__device__ __forceinline__ unsigned pkbf2(float a, float b) {
#if __has_builtin(__builtin_amdgcn_cvt_pk_bf16_f32)
    auto p = __builtin_amdgcn_cvt_pk_bf16_f32(a, b);
    unsigned q; __builtin_memcpy(&q, &p, 4); return q;
#else
    union { float f; unsigned u; } x, y; x.f = a; y.f = b;
    unsigned ua = (x.u + 0x7fffu + ((x.u >> 16) & 1u)) >> 16;
    unsigned ub = (y.u + 0x7fffu + ((y.u >> 16) & 1u)) & 0xffff0000u;
    return ua | ub;
#endif
}
__device__ __forceinline__ void st4(short* dst, const f32x4& v) {
    uint2 q; q.x = pkbf2(v[0], v[1]); q.y = pkbf2(v[2], v[3]);
    *(uint2*)dst = q;
}
__device__ __forceinline__ f32x4 exp24(f32x4 a) {
    f32x4 r;
    #pragma unroll
    for (int i = 0; i < 4; ++i) r[i] = EXP2F(a[i]);
    return r;
}
// tanh of one vector: denominators paired (0,1),(2,3) -> 2 rcp instead of 4.
// tanh(x) computed as 1 - 2/(e^{2x}+1); input is pre-scaled by 2*LOG2E.
__device__ __forceinline__ f32x4 tanh1(const f32x4& a) {
    f32x4 E = exp24(a) + 1.0f, t;
    #pragma unroll
    for (int i = 0; i < 4; i += 2) {
        float R = __builtin_amdgcn_rcpf(E[i]*E[i+1]);
        t[i]   = 1.0f - 2.0f*(R*E[i+1]);
        t[i+1] = 1.0f - 2.0f*(R*E[i]);
    }
    return t;
}
// tanh of two vectors: pair elementwise across the two -> 4 rcp instead of 8.
__device__ __forceinline__ void tanh2(const f32x4& a, const f32x4& b, f32x4& ta, f32x4& tb) {
    f32x4 Ea = exp24(a) + 1.0f, Eb = exp24(b) + 1.0f;
    #pragma unroll
    for (int i = 0; i < 4; ++i) {
        float R = __builtin_amdgcn_rcpf(Ea[i]*Eb[i]);
        ta[i] = 1.0f - 2.0f*(R*Eb[i]);
        tb[i] = 1.0f - 2.0f*(R*Ea[i]);
    }
}

// ---------------- prep: W1/W2 as A-operand fragments (bf16, W1 pre-scaled) ----
__global__ void prep_frags(const float* __restrict__ W1, const float* __restrict__ W2,
                           short* __restrict__ w1f, short* __restrict__ w2f)
{
    int tid0 = blockIdx.x*256 + threadIdx.x;
    for (int idx = tid0; idx < 16*4*64*8; idx += 8*256) {
        int j = idx & 7, lane = (idx >> 3) & 63, kc = (idx >> 9) & 3, t = idx >> 11;
        int row = t*16 + (lane & 15);
        int k   = kc*32 + (lane >> 4)*8 + j;
        w1f[idx] = f2bf(2.0f*LOG2E*W1[row*NH + k]);
    }
    for (int idx = tid0; idx < 8*64*8; idx += 8*256) {
        int j = idx & 7, lane = (idx >> 3) & 63, kc = idx >> 9;
        int m = lane & 15;
        int k = kc*32 + (lane >> 4)*8 + j;
        w2f[idx] = (m < NKOUT) ? f2bf(W2[m*2*NH + k]) : (short)0;
    }
}

// ---------------- fused kernel helpers ----------------
__device__ __forceinline__ void ld4(const short* bp, short8 (&bf)[4]) {
    #pragma unroll
    for (int kc = 0; kc < 4; ++kc) bf[kc] = *(const short8*)(bp + kc*32);
}
__device__ __forceinline__ void gemmR(const short8 (&bf)[4], const short8 (&A)[3][4],
                                      f32x4 (&acc)[3]) {
    #pragma unroll
    for (int kc = 0; kc < 4; ++kc)
        #pragma unroll
        for (int g = 0; g < 3; ++g)
            acc[g] = __builtin_amdgcn_mfma_f32_16x16x32_bf16(A[g][kc], bf[kc], acc[g], 0, 0, 0);
}
__device__ __forceinline__ void gemmB(const short* bp, const short8 (&A)[3][4], f32x4 (&acc)[3]) {
    short8 bf[4]; ld4(bp, bf); gemmR(bf, A, acc);
}
// r-gate scaled -LOG2E (rg = sigmoid), z-gate scaled +LOG2E (zc = 1-z),
// n-gate scaled 2*LOG2E (tanh). K = (1-z)*(n - y).
// Reciprocal pairing: r/z denominators are independent -> 1 rcp for both.
__device__ __forceinline__ void gateK(const f32x4 (&gi)[3], const f32x4 (&gh)[3],
                                      const f32x4& yin, f32x4& K)
{
    f32x4 Ea = exp24(gi[0] + gh[0]) + 1.0f;   // r denom
    f32x4 Eb = exp24(gi[1] + gh[1]) + 1.0f;   // z denom
    f32x4 rg, zc;
    #pragma unroll
    for (int i = 0; i < 4; ++i) {
        float R = __builtin_amdgcn_rcpf(Ea[i]*Eb[i]);
        rg[i] = R*Eb[i];
        zc[i] = R*Ea[i];
    }
    f32x4 Ec = exp24(gi[2] + rg*gh[2]) + 1.0f;
    f32x4 tg;
    #pragma unroll
    for (int i = 0; i < 4; i += 2) {
        float R = __builtin_amdgcn_rcpf(Ec[i]*Ec[i+1]);
        tg[i]   = 1.0f - 2.0f*(R*Ec[i+1]);
        tg[i+1] = 1.0f - 2.0f*(R*Ec[i]);
    }
    K = zc*(tg - yin);
}

// 2 blocks/CU: grid 512, 8 real batch cols per block (MFMA cols 8-15 carry
// finite/contained garbage, never stored). NOTE __launch_bounds__ 2nd arg is
// CUDA-semantics min BLOCKS/CU on hipcc (measured: (512,4) -> 64 VGPR + spill
// disaster; (512,2) -> 128 VGPR, no spill). (512,2) caps at 128 VGPR which is
// exactly 2 co-resident 8-wave blocks per CU.
__global__ void __launch_bounds__(512, 2)
fused_kernel(const float* __restrict__ pre_x, const float* __restrict__ pre_y,
             const float* __restrict__ fx,
             const float* __restrict__ W_ih, const float* __restrict__ W_hh,
             const float* __restrict__ b_ih, const float* __restrict__ b_hh,
             const float* __restrict__ W_e,  const float* __restrict__ b_e,
             const float* __restrict__ Wc_ih,const float* __restrict__ Wc_hh,
             const float* __restrict__ bc_ih,const float* __restrict__ bc_hh,
             float* __restrict__ UM,         const short* __restrict__ w1f,
             const short* __restrict__ w2f,  float* __restrict__ out)
{
    __shared__ __align__(16) short yTa[16*136];   // enc ping / RK4 y
    __shared__ __align__(16) short yTb[16*136];   // enc pong / RK4 ye1, ye3
    __shared__ __align__(16) short E1 [16*136];   // spline cp (prologue) / ye2
    __shared__ __align__(16) short xmT[16*136];
    __shared__ __align__(16) short x1T[16*136];
    __shared__ __align__(16) short UMb[16*40];
    __shared__ __align__(16) short U1b[16*40];
    __shared__ __align__(16) short oT [16*264];
    __shared__ __align__(16) short w2S[8*64*8];   // W2 A-frags resident in LDS (8 KB)

    const int tid  = threadIdx.x;
    const int w    = tid >> 6;
    const int lane = tid & 63;
    const int quad = lane >> 4;
    const int m    = lane & 15;
    const int hq   = w*16 + quad*4;
    const int b0   = blockIdx.x * NBT;
    const f32x4 z4 = {0.f, 0.f, 0.f, 0.f};
    const float scg[3] = {-LOG2E, LOG2E, 2.0f*LOG2E};   // r, z(flipped), n

    for (int i = tid; i < 16*136; i += 512) yTa[i] = 0;
    for (int i = tid; i < 16*40;  i += 512) { UMb[i] = 0; U1b[i] = 0; }
    ((short8*)w2S)[tid & 511] = ((const short8*)w2f)[tid & 511];   // 512 frags, 1/thread

    f32x4 y = z4;

    // ================= encoder GRU: 1 fast barrier/step =================
    {
        short8 Ehh[3][4];
        #pragma unroll
        for (int g = 0; g < 3; ++g)
            #pragma unroll
            for (int c = 0; c < 4; ++c) {
                const float* ph = W_hh + (size_t)(g*NH + w*16 + m)*NH + c*32 + quad*8;
                short8 fh;
                #pragma unroll
                for (int j = 0; j < 8; ++j) fh[j] = f2bf(scg[g]*ph[j]);
                Ehh[g][c] = fh;
            }
        short8 Eih[3];
        #pragma unroll
        for (int g = 0; g < 3; ++g) {
            short8 f1;
            #pragma unroll
            for (int j = 0; j < 8; ++j) {
                int k = quad*8 + j;
                f1[j] = (k < 12) ? f2bf(scg[g]*W_ih[(size_t)(g*NH + w*16 + m)*12 + k]) : (short)0;
            }
            Eih[g] = f1;
        }
        f32x4 erz4, ezz4, egn4, ein4;
        #pragma unroll
        for (int r = 0; r < 4; ++r) {
            int h = hq + r;
            erz4[r] = -LOG2E*(b_ih[h]      + b_hh[h]);
            ezz4[r] =  LOG2E*(b_ih[NH + h] + b_hh[NH + h]);
            egn4[r] = 2.0f*LOG2E*b_hh[2*NH + h];
            ein4[r] = 2.0f*LOG2E*b_ih[2*NH + h];
        }
        // staging: wave w stages batch col w; lanes 0-11 carry the 12 inputs
        const int eb = w, ek = lane;
        const bool estg = (lane < 12);
        float encv = 0.f;
        if (estg) {
            float e0 = (ek < NKIN) ? pre_x[((size_t)0*NB + b0 + eb)*NKIN + ek]
                                   : pre_y[((size_t)0*NB + b0 + eb)*NKOUT + (ek - NKIN)];
            UMb[eb*40 + ek] = f2bf(e0);
            encv = (ek < NKIN) ? pre_x[((size_t)1*NB + b0 + eb)*NKIN + ek]
                               : pre_y[((size_t)1*NB + b0 + eb)*NKOUT + (ek - NKIN)];
        }
        BAR();
        for (int t = 0; t < NTP; ++t) {
            float evn = 0.f;
            if (estg) {
                int tn = (t + 2 < NTP) ? t + 2 : NTP - 1;
                evn = (ek < NKIN) ? pre_x[((size_t)tn*NB + b0 + eb)*NKIN + ek]
                                  : pre_y[((size_t)tn*NB + b0 + eb)*NKOUT + (ek - NKIN)];
            }
            const short* bin_buf  = (t & 1) ? U1b : UMb;
            short*       bout_buf = (t & 1) ? UMb : U1b;
            const short* sin_buf  = (t & 1) ? yTb : yTa;
            short*       sout_buf = (t & 1) ? yTa : yTb;
            f32x4 gi[3] = {z4, z4, ein4};
            {
                short8 b = *(const short8*)(bin_buf + m*40 + quad*8);
                #pragma unroll
                for (int g = 0; g < 3; ++g)
                    gi[g] = __builtin_amdgcn_mfma_f32_16x16x32_bf16(Eih[g], b, gi[g], 0, 0, 0);
            }
            f32x4 gh[3] = {erz4, ezz4, egn4};
            gemmB(sin_buf + m*136 + quad*8, Ehh, gh);
            f32x4 K;
            gateK(gi, gh, y, K);
            y += K;
            st4(sout_buf + m*136 + hq, y);
            if (estg) { bout_buf[eb*40 + ek] = f2bf(encv); encv = evn; }
            BAR();
        }
    }
    // y(0) in regs; final enc state in yTa (t=63 odd wrote yTa)

    // ---- persistent RK4 A-frags ----
    short8 Ahh[3][4], Aih[3][4];
    #pragma unroll
    for (int g = 0; g < 3; ++g)
        #pragma unroll
        for (int c = 0; c < 4; ++c) {
            const float* ph = Wc_hh + (size_t)(g*NH + w*16 + m)*NH + c*32 + quad*8;
            const float* pi = Wc_ih + (size_t)(g*NH + w*16 + m)*NH + c*32 + quad*8;
            short8 fh, fi;
            #pragma unroll
            for (int j = 0; j < 8; ++j) { fh[j] = f2bf(scg[g]*ph[j]); fi[j] = f2bf(scg[g]*pi[j]); }
            Ahh[g][c] = fh; Aih[g][c] = fi;
        }
    short8 Aexp;
    #pragma unroll
    for (int j = 0; j < 8; ++j) {
        int k = quad*8 + j;
        Aexp[j] = (k < NKIN) ? f2bf(2.0f*LOG2E*W_e[(w*16 + m)*NKIN + k]) : (short)0;
    }
    short8 A1f[2][4];
    #pragma unroll
    for (int kc = 0; kc < 4; ++kc) {
        A1f[0][kc] = *(const short8*)(w1f + (size_t)(((w    )*4 + kc)*64 + lane)*8);
        A1f[1][kc] = *(const short8*)(w1f + (size_t)(((w + 8)*4 + kc)*64 + lane)*8);
    }
    f32x4 brz4, bzz4, bgn4, bin4, be4;
    #pragma unroll
    for (int r = 0; r < 4; ++r) {
        int h = hq + r;
        brz4[r] = -LOG2E*(bc_ih[h]      + bc_hh[h]);
        bzz4[r] =  LOG2E*(bc_ih[NH + h] + bc_hh[NH + h]);
        bgn4[r] = 2.0f*LOG2E*bc_hh[2*NH + h];
        bin4[r] = 2.0f*LOG2E*bc_ih[2*NH + h];
        be4[r]  = 2.0f*LOG2E*b_e[h];
    }

    // ================= in-kernel spline (Thomas, reversed elimination) =================
    // wave w owns batch col w; lanes 0-7 own the 8 input channels
    const bool stg = (lane < 8);
    const int sb = w, sk = lane;
    const size_t scol = (size_t)(b0 + sb)*NKIN + sk;   // only valid for stg lanes
    float* cpS = (float*)E1;
    float prex_last = 0.f;
    if (stg) prex_last = pre_x[(size_t)(NTP-1)*BKIN + scol];
    if (stg) {
        const float r6 = 6.0f/(0.1f*0.1f);
        float c = 0.f, d = 0.f;
        float yp = fx[(size_t)127*BKIN + scol];
        float y0 = fx[(size_t)126*BKIN + scol];
        float ym = fx[(size_t)125*BKIN + scol];
        #pragma unroll 4
        for (int j = 127; j >= 1; --j) {
            float r = r6*(ym - 2.f*y0 + yp);
            c = __builtin_amdgcn_rcpf(4.f - c);
            d = (r - d)*c;
            UM[(size_t)j*BKIN + scol] = d;
            if (tid == 0) cpS[128 - j] = c;
            yp = y0; y0 = ym;
            ym = (j >= 3) ? fx[(size_t)(j-3)*BKIN + scol] : prex_last;
        }
    }
    __syncthreads();   // FULL: same-thread global RAW on UM
    if (stg) {
        const float KK = 0.01f/16.0f;
        float Mp = 0.f;
        float y0 = prex_last;
        float y1 = fx[scol];
        #pragma unroll 4
        for (int j = 1; j <= 127; ++j) {
            float dj = UM[(size_t)j*BKIN + scol];
            float e  = cpS[128 - j];
            float Mj = dj - e*Mp;
            UM[(size_t)(j-1)*BKIN + scol] = 0.5f*(y0 + y1) - KK*(Mp + Mj);
            Mp = Mj; y0 = y1;
            y1 = fx[(size_t)j*BKIN + scol];
        }
        UM[(size_t)127*BKIN + scol] = 0.5f*(y0 + y1) - KK*Mp;
    }
    __syncthreads();   // FULL: UM writes drained; E1 free again

    // ================= RK4 prologue =================
    if (stg) {
        UMb[sb*40 + 8 + (lane & 3)] = 0;
        U1b[sb*40 + 8 + (lane & 3)] = 0;
        UMb[sb*40 + sk] = f2bf(prex_last);
    }
    BAR();
    {   // x0 = tanh-expand(u0_start) -> xmT
        short8 b = *(const short8*)(UMb + m*40 + quad*8);
        f32x4 c0 = be4;
        c0 = __builtin_amdgcn_mfma_f32_16x16x32_bf16(Aexp, b, c0, 0, 0, 0);
        f32x4 xv = tanh1(c0);
        st4(xmT + m*136 + hq, xv);
    }
    BAR();
    f32x4 gi0[3] = {z4, z4, bin4};
    gemmB(xmT + m*136 + quad*8, Aih, gi0);
    if (stg) { UMb[sb*40 + sk] = f2bf(UM[scol]); U1b[sb*40 + sk] = f2bf(fx[scol]); }
    BAR();
    {   // expand u(0) -> xmT, x1T
        short8 bm = *(const short8*)(UMb + m*40 + quad*8);
        short8 b1 = *(const short8*)(U1b + m*40 + quad*8);
        f32x4 cm = be4, c1 = be4;
        cm = __builtin_amdgcn_mfma_f32_16x16x32_bf16(Aexp, bm, cm, 0, 0, 0);
        c1 = __builtin_amdgcn_mfma_f32_16x16x32_bf16(Aexp, b1, c1, 0, 0, 0);
        f32x4 xm, x1;
        tanh2(cm, c1, xm, x1);
        st4(xmT + m*136 + hq, xm);
        st4(x1T + m*136 + hq, x1);
    }
    float fxv = 0.f, umv = 0.f;
    if (stg) { fxv = fx[(size_t)BKIN + scol]; umv = UM[(size_t)BKIN + scol]; }  // u(1)
    BAR();
    f32x4 gim[3] = {z4, z4, bin4}, gi1[3] = {z4, z4, bin4};
    gemmB(xmT + m*136 + quad*8, Aih, gim);
    gemmB(x1T + m*136 + quad*8, Aih, gi1);

    // ================= RK4 loop: 4 fast barriers/step =================
    // P1 = k1 + head1(st-1) | P2 = k2 + stage2(st-1) + staging u(st+1)
    // P3 = k3 + expand(st+1) | P4 = k4 + y-upd + gim/gi1(st+1) + prefetch u(st+2)
    for (int st = 0; st < NL; ++st) {
        // ---- P1: k1 + head1(st-1) (shared yTa read) ----
        short8 byf[4];
        ld4(yTa + m*136 + quad*8, byf);
        f32x4 gh[3] = {brz4, bzz4, bgn4};
        gemmR(byf, Ahh, gh);
        if (st > 0) {
            f32x4 o0 = z4, o1 = z4;
            #pragma unroll
            for (int kc = 0; kc < 4; ++kc) {
                o0 = __builtin_amdgcn_mfma_f32_16x16x32_bf16(A1f[0][kc], byf[kc], o0, 0, 0, 0);
                o1 = __builtin_amdgcn_mfma_f32_16x16x32_bf16(A1f[1][kc], byf[kc], o1, 0, 0, 0);
            }
            f32x4 t0, t1;
            tanh2(o0, o1, t0, t1);
            st4(oT + m*264 + w*16     + quad*4, t0);
            st4(oT + m*264 + (w+8)*16 + quad*4, t1);
        }
        f32x4 K, Ks, ye;
        gateK(gi0, gh, y, K);
        Ks = K; ye = y + 0.5f*K;
        st4(yTb + m*136 + hq, ye);
        BAR();                                                  // B1
        // ---- P2: k2 + stage2(st-1) + staging u(st+1) ----
        if (stg) { UMb[sb*40 + sk] = f2bf(umv); U1b[sb*40 + sk] = f2bf(fxv); }
        gh[0] = brz4; gh[1] = bzz4; gh[2] = bgn4;
        gemmB(yTb + m*136 + quad*8, Ahh, gh);
        if (st > 0 && w == ((st-1) & 7)) {
            f32x4 oc = z4;
            #pragma unroll
            for (int kc = 0; kc < 8; ++kc) {
                short8 a2 = *(const short8*)(w2S + (kc*64 + lane)*8);
                short8 b  = *(const short8*)(oT + m*264 + kc*32 + quad*8);
                oc = __builtin_amdgcn_mfma_f32_16x16x32_bf16(a2, b, oc, 0, 0, 0);
            }
            if (quad == 0 && m < NBT)
                *(f32x4*)(out + ((size_t)(st-1)*NB + b0 + m)*NKOUT) = oc;
        }
        gateK(gim, gh, ye, K);
        Ks += 2.0f*K; ye = y + 0.5f*K;
        st4(E1 + m*136 + hq, ye);
        BAR();                                                  // B2
        // ---- P3: k3 + expand(st+1) ----
        gh[0] = brz4; gh[1] = bzz4; gh[2] = bgn4;
        gemmB(E1 + m*136 + quad*8, Ahh, gh);
        {
            short8 bm = *(const short8*)(UMb + m*40 + quad*8);
            short8 b1 = *(const short8*)(U1b + m*40 + quad*8);
            f32x4 cm = be4, c1 = be4;
            cm = __builtin_amdgcn_mfma_f32_16x16x32_bf16(Aexp, bm, cm, 0, 0, 0);
            c1 = __builtin_amdgcn_mfma_f32_16x16x32_bf16(Aexp, b1, c1, 0, 0, 0);
            f32x4 xm, x1;
            tanh2(cm, c1, xm, x1);
            st4(xmT + m*136 + hq, xm);
            st4(x1T + m*136 + hq, x1);
        }
        gateK(gim, gh, ye, K);
        Ks += 2.0f*K; ye = y + K;
        st4(yTb + m*136 + hq, ye);
        BAR();                                                  // B3
        // ---- P4: k4 + y update + gim/gi1(st+1) + prefetch u(st+2) ----
        if (stg) {
            int sn = (st + 2 < NL) ? st + 2 : NL - 1;
            fxv = fx[(size_t)sn*BKIN + scol];
            umv = UM[(size_t)sn*BKIN + scol];
        }
        gh[0] = brz4; gh[1] = bzz4; gh[2] = bgn4;
        gemmB(yTb + m*136 + quad*8, Ahh, gh);
        gateK(gi1, gh, ye, K);
        y += (1.0f/6.0f)*(Ks + K);
        st4(yTa + m*136 + hq, y);
        gi0[0] = gi1[0]; gi0[1] = gi1[1]; gi0[2] = gi1[2];
        gim[0] = z4; gim[1] = z4; gim[2] = bin4;
        gi1[0] = z4; gi1[1] = z4; gi1[2] = bin4;
        gemmB(xmT + m*136 + quad*8, Aih, gim);
        gemmB(x1T + m*136 + quad*8, Aih, gi1);
        BAR();                                                  // B4
    }

    // ================= epilogue: head + stage2 for out[127] =================
    {
        short8 byf[4];
        ld4(yTa + m*136 + quad*8, byf);
        f32x4 o0 = z4, o1 = z4;
        #pragma unroll
        for (int kc = 0; kc < 4; ++kc) {
            o0 = __builtin_amdgcn_mfma_f32_16x16x32_bf16(A1f[0][kc], byf[kc], o0, 0, 0, 0);
            o1 = __builtin_amdgcn_mfma_f32_16x16x32_bf16(A1f[1][kc], byf[kc], o1, 0, 0, 0);
        }
        f32x4 t0, t1;
        tanh2(o0, o1, t0, t1);
        st4(oT + m*264 + w*16     + quad*4, t0);
        st4(oT + m*264 + (w+8)*16 + quad*4, t1);
        BAR();
        if (w == 7) {
            f32x4 oc = z4;
            #pragma unroll
            for (int kc = 0; kc < 8; ++kc) {
                short8 a2 = *(const short8*)(w2S + (kc*64 + lane)*8);
                short8 b  = *(const short8*)(oT + m*264 + kc*32 + quad*8);
                oc = __builtin_amdgcn_mfma_f32_16x16x32_bf16(a2, b, oc, 0, 0, 0);
            }
            if (quad == 0 && m < NBT)
                *(f32x4*)(out + ((size_t)(NL-1)*NB + b0 + m)*NKOUT) = oc;
        }
    }
}

extern "C" void kernel_launch(void* const* d_in, const int* in_sizes, int n_in,
                              void* d_out, int out_size, void* d_ws, size_t ws_size,
                              hipStream_t stream)
{
    const float* pre_x = (const float*)d_in[0];
    const float* pre_y = (const float*)d_in[1];
    const float* fx    = (const float*)d_in[2];
    const float* W_ih  = (const float*)d_in[3];
    const float* W_hh  = (const float*)d_in[4];
    const float* b_ih  = (const float*)d_in[5];
    const float* b_hh  = (const float*)d_in[6];
    const float* W_e   = (const float*)d_in[7];
    const float* b_e   = (const float*)d_in[8];
    const float* Wc_ih = (const float*)d_in[9];
    const float* Wc_hh = (const float*)d_in[10];
    const float* bc_ih = (const float*)d_in[11];
    const float* bc_hh = (const float*)d_in[12];
    const float* W1    = (const float*)d_in[13];
    const float* W2    = (const float*)d_in[14];
    float* out = (float*)d_out;

    float* UM  = (float*)d_ws;                                  // 128*4096*8 fp32 = 16.78 MB
    short* w1f = (short*)((char*)d_ws + (size_t)NL*NB*NKIN*4);  // 32768 shorts
    short* w2f = w1f + 16*4*64*8;                               // 4096 shorts

    prep_frags<<<dim3(8), dim3(256), 0, stream>>>(W1, W2, w1f, w2f);
    fused_kernel<<<dim3(NB/NBT), dim3(512), 0, stream>>>(
        pre_x, pre_y, fx, W_ih, W_hh, b_ih, b_hh, W_e, b_e,
        Wc_ih, Wc_hh, bc_ih, bc_hh, UM, w1f, w2f, out);
}

// Round 4
// 692.121 us; speedup vs baseline: 6.3309x; 1.8547x over previous
//
#include <hip/hip_runtime.h>
#include <math.h>

#define NB    4096
#define NH    128
#define NKIN  8
#define NKOUT 4
#define NTP   64
#define NL    128
#define BKIN  (NB*NKIN)
#define LOG2E 1.44269504088896340736f

// lgkm-only barrier: orders LDS ops across the block WITHOUT draining in-flight
// global loads. Safe: loops have no cross-thread global dependencies.
#define BAR() asm volatile("s_waitcnt lgkmcnt(0)\n\ts_barrier" ::: "memory")

typedef __attribute__((ext_vector_type(8))) short short8;
typedef __attribute__((ext_vector_type(4))) float f32x4;

#if __has_builtin(__builtin_amdgcn_exp2f)
#define EXP2F __builtin_amdgcn_exp2f
#else
#define EXP2F exp2f
#endif

__device__ __forceinline__ short f2bf(float f) {
    union { float f; unsigned u; } v; v.f = f;
    unsigned u = v.u;
    return (short)((u + 0x7fffu + ((u >> 16) & 1u)) >> 16);
}
__device__ __forceinline__ unsigned pkbf2(float a, float b) {
#if __has_builtin(__builtin_amdgcn_cvt_pk_bf16_f32)
    auto p = __builtin_amdgcn_cvt_pk_bf16_f32(a, b);
    unsigned q; __builtin_memcpy(&q, &p, 4); return q;
#else
    union { float f; unsigned u; } x, y; x.f = a; y.f = b;
    unsigned ua = (x.u + 0x7fffu + ((x.u >> 16) & 1u)) >> 16;
    unsigned ub = (y.u + 0x7fffu + ((y.u >> 16) & 1u)) & 0xffff0000u;
    return ua | ub;
#endif
}
__device__ __forceinline__ void st4(short* dst, const f32x4& v) {
    uint2 q; q.x = pkbf2(v[0], v[1]); q.y = pkbf2(v[2], v[3]);
    *(uint2*)dst = q;
}
__device__ __forceinline__ f32x4 exp24(f32x4 a) {
    f32x4 r;
    #pragma unroll
    for (int i = 0; i < 4; ++i) r[i] = EXP2F(a[i]);
    return r;
}
// tanh of one vector: denominators paired (0,1),(2,3) -> 2 rcp instead of 4.
// tanh(x) computed as 1 - 2/(e^{2x}+1); input is pre-scaled by 2*LOG2E.
__device__ __forceinline__ f32x4 tanh1(const f32x4& a) {
    f32x4 E = exp24(a) + 1.0f, t;
    #pragma unroll
    for (int i = 0; i < 4; i += 2) {
        float R = __builtin_amdgcn_rcpf(E[i]*E[i+1]);
        t[i]   = 1.0f - 2.0f*(R*E[i+1]);
        t[i+1] = 1.0f - 2.0f*(R*E[i]);
    }
    return t;
}
// tanh of two vectors: pair elementwise across the two -> 4 rcp instead of 8.
__device__ __forceinline__ void tanh2(const f32x4& a, const f32x4& b, f32x4& ta, f32x4& tb) {
    f32x4 Ea = exp24(a) + 1.0f, Eb = exp24(b) + 1.0f;
    #pragma unroll
    for (int i = 0; i < 4; ++i) {
        float R = __builtin_amdgcn_rcpf(Ea[i]*Eb[i]);
        ta[i] = 1.0f - 2.0f*(R*Eb[i]);
        tb[i] = 1.0f - 2.0f*(R*Ea[i]);
    }
}

// ---------------- prep: W1/W2 as A-operand fragments (bf16, W1 pre-scaled) ----
__global__ void prep_frags(const float* __restrict__ W1, const float* __restrict__ W2,
                           short* __restrict__ w1f, short* __restrict__ w2f)
{
    int tid0 = blockIdx.x*256 + threadIdx.x;
    for (int idx = tid0; idx < 16*4*64*8; idx += 8*256) {
        int j = idx & 7, lane = (idx >> 3) & 63, kc = (idx >> 9) & 3, t = idx >> 11;
        int row = t*16 + (lane & 15);
        int k   = kc*32 + (lane >> 4)*8 + j;
        w1f[idx] = f2bf(2.0f*LOG2E*W1[row*NH + k]);
    }
    for (int idx = tid0; idx < 8*64*8; idx += 8*256) {
        int j = idx & 7, lane = (idx >> 3) & 63, kc = idx >> 9;
        int m = lane & 15;
        int k = kc*32 + (lane >> 4)*8 + j;
        w2f[idx] = (m < NKOUT) ? f2bf(W2[m*2*NH + k]) : (short)0;
    }
}

// ---------------- fused kernel helpers ----------------
__device__ __forceinline__ void ld4(const short* bp, short8 (&bf)[4]) {
    #pragma unroll
    for (int kc = 0; kc < 4; ++kc) bf[kc] = *(const short8*)(bp + kc*32);
}
__device__ __forceinline__ void gemmR(const short8 (&bf)[4], const short8 (&A)[3][4],
                                      f32x4 (&acc)[3]) {
    #pragma unroll
    for (int kc = 0; kc < 4; ++kc)
        #pragma unroll
        for (int g = 0; g < 3; ++g)
            acc[g] = __builtin_amdgcn_mfma_f32_16x16x32_bf16(A[g][kc], bf[kc], acc[g], 0, 0, 0);
}
__device__ __forceinline__ void gemmB(const short* bp, const short8 (&A)[3][4], f32x4 (&acc)[3]) {
    short8 bf[4]; ld4(bp, bf); gemmR(bf, A, acc);
}
// r-gate scaled -LOG2E (rg = sigmoid), z-gate scaled +LOG2E (zc = 1-z),
// n-gate scaled 2*LOG2E (tanh). K = (1-z)*(n - y).
// Reciprocal pairing: r/z denominators are independent -> 1 rcp for both.
__device__ __forceinline__ void gateK(const f32x4 (&gi)[3], const f32x4 (&gh)[3],
                                      const f32x4& yin, f32x4& K)
{
    f32x4 Ea = exp24(gi[0] + gh[0]) + 1.0f;   // r denom
    f32x4 Eb = exp24(gi[1] + gh[1]) + 1.0f;   // z denom
    f32x4 rg, zc;
    #pragma unroll
    for (int i = 0; i < 4; ++i) {
        float R = __builtin_amdgcn_rcpf(Ea[i]*Eb[i]);
        rg[i] = R*Eb[i];
        zc[i] = R*Ea[i];
    }
    f32x4 Ec = exp24(gi[2] + rg*gh[2]) + 1.0f;
    f32x4 tg;
    #pragma unroll
    for (int i = 0; i < 4; i += 2) {
        float R = __builtin_amdgcn_rcpf(Ec[i]*Ec[i+1]);
        tg[i]   = 1.0f - 2.0f*(R*Ec[i+1]);
        tg[i+1] = 1.0f - 2.0f*(R*Ec[i]);
    }
    K = zc*(tg - yin);
}

// Occupancy note (measured r2/r3): effective per-wave alloc is ~256 regs
// (128 arch VGPR + ~128 AGPR, unified file) -> 2 waves/SIMD -> exactly ONE
// 8-wave block per CU. grid 256 = 1 block/CU is the operating point.
// __launch_bounds__ 2nd arg is min-BLOCKS/CU (CUDA semantics) on hipcc:
// (512,4) forced 64 VGPR + catastrophic spill; (512,2) -> 128 VGPR, no spill.
__global__ void __launch_bounds__(512, 2)
fused_kernel(const float* __restrict__ pre_x, const float* __restrict__ pre_y,
             const float* __restrict__ fx,
             const float* __restrict__ W_ih, const float* __restrict__ W_hh,
             const float* __restrict__ b_ih, const float* __restrict__ b_hh,
             const float* __restrict__ W_e,  const float* __restrict__ b_e,
             const float* __restrict__ Wc_ih,const float* __restrict__ Wc_hh,
             const float* __restrict__ bc_ih,const float* __restrict__ bc_hh,
             float* __restrict__ UM,         const short* __restrict__ w1f,
             const short* __restrict__ w2f,  float* __restrict__ out)
{
    __shared__ __align__(16) short yTa[16*136];   // enc ping / RK4 y
    __shared__ __align__(16) short yTb[16*136];   // enc pong / RK4 ye1, ye3
    __shared__ __align__(16) short E1 [16*136];   // spline cp (prologue) / ye2
    __shared__ __align__(16) short xmT[16*136];
    __shared__ __align__(16) short x1T[16*136];
    __shared__ __align__(16) short UMb[16*40];
    __shared__ __align__(16) short U1b[16*40];
    __shared__ __align__(16) short oT [16*264];
    __shared__ __align__(16) short w2S[8*64*8];   // W2 A-frags resident in LDS (8 KB)

    const int tid  = threadIdx.x;
    const int w    = tid >> 6;
    const int lane = tid & 63;
    const int quad = lane >> 4;
    const int m    = lane & 15;
    const int hq   = w*16 + quad*4;
    const int b0   = blockIdx.x * 16;
    const f32x4 z4 = {0.f, 0.f, 0.f, 0.f};
    const float scg[3] = {-LOG2E, LOG2E, 2.0f*LOG2E};   // r, z(flipped), n

    for (int i = tid; i < 16*136; i += 512) yTa[i] = 0;
    for (int i = tid; i < 16*40;  i += 512) { UMb[i] = 0; U1b[i] = 0; }
    ((short8*)w2S)[tid & 511] = ((const short8*)w2f)[tid & 511];   // 512 frags, 1/thread

    f32x4 y = z4;

    // ================= encoder GRU: 1 fast barrier/step =================
    {
        short8 Ehh[3][4];
        #pragma unroll
        for (int g = 0; g < 3; ++g)
            #pragma unroll
            for (int c = 0; c < 4; ++c) {
                const float* ph = W_hh + (size_t)(g*NH + w*16 + m)*NH + c*32 + quad*8;
                short8 fh;
                #pragma unroll
                for (int j = 0; j < 8; ++j) fh[j] = f2bf(scg[g]*ph[j]);
                Ehh[g][c] = fh;
            }
        short8 Eih[3];
        #pragma unroll
        for (int g = 0; g < 3; ++g) {
            short8 f1;
            #pragma unroll
            for (int j = 0; j < 8; ++j) {
                int k = quad*8 + j;
                f1[j] = (k < 12) ? f2bf(scg[g]*W_ih[(size_t)(g*NH + w*16 + m)*12 + k]) : (short)0;
            }
            Eih[g] = f1;
        }
        f32x4 erz4, ezz4, egn4, ein4;
        #pragma unroll
        for (int r = 0; r < 4; ++r) {
            int h = hq + r;
            erz4[r] = -LOG2E*(b_ih[h]      + b_hh[h]);
            ezz4[r] =  LOG2E*(b_ih[NH + h] + b_hh[NH + h]);
            egn4[r] = 2.0f*LOG2E*b_hh[2*NH + h];
            ein4[r] = 2.0f*LOG2E*b_ih[2*NH + h];
        }
        const int eidx = w*24 + lane;
        const int eb = eidx/12, ek = eidx - 12*eb;
        const bool estg = (lane < 24);
        float encv = 0.f;
        if (estg) {
            float e0 = (ek < NKIN) ? pre_x[((size_t)0*NB + b0 + eb)*NKIN + ek]
                                   : pre_y[((size_t)0*NB + b0 + eb)*NKOUT + (ek - NKIN)];
            UMb[eb*40 + ek] = f2bf(e0);
            encv = (ek < NKIN) ? pre_x[((size_t)1*NB + b0 + eb)*NKIN + ek]
                               : pre_y[((size_t)1*NB + b0 + eb)*NKOUT + (ek - NKIN)];
        }
        BAR();
        for (int t = 0; t < NTP; ++t) {
            float evn = 0.f;
            if (estg) {
                int tn = (t + 2 < NTP) ? t + 2 : NTP - 1;
                evn = (ek < NKIN) ? pre_x[((size_t)tn*NB + b0 + eb)*NKIN + ek]
                                  : pre_y[((size_t)tn*NB + b0 + eb)*NKOUT + (ek - NKIN)];
            }
            const short* bin_buf  = (t & 1) ? U1b : UMb;
            short*       bout_buf = (t & 1) ? UMb : U1b;
            const short* sin_buf  = (t & 1) ? yTb : yTa;
            short*       sout_buf = (t & 1) ? yTa : yTb;
            f32x4 gi[3] = {z4, z4, ein4};
            {
                short8 b = *(const short8*)(bin_buf + m*40 + quad*8);
                #pragma unroll
                for (int g = 0; g < 3; ++g)
                    gi[g] = __builtin_amdgcn_mfma_f32_16x16x32_bf16(Eih[g], b, gi[g], 0, 0, 0);
            }
            f32x4 gh[3] = {erz4, ezz4, egn4};
            gemmB(sin_buf + m*136 + quad*8, Ehh, gh);
            f32x4 K;
            gateK(gi, gh, y, K);
            y += K;
            st4(sout_buf + m*136 + hq, y);
            if (estg) { bout_buf[eb*40 + ek] = f2bf(encv); encv = evn; }
            BAR();
        }
    }
    // y(0) in regs; final enc state in yTa (t=63 odd wrote yTa)

    // ---- persistent RK4 A-frags ----
    short8 Ahh[3][4], Aih[3][4];
    #pragma unroll
    for (int g = 0; g < 3; ++g)
        #pragma unroll
        for (int c = 0; c < 4; ++c) {
            const float* ph = Wc_hh + (size_t)(g*NH + w*16 + m)*NH + c*32 + quad*8;
            const float* pi = Wc_ih + (size_t)(g*NH + w*16 + m)*NH + c*32 + quad*8;
            short8 fh, fi;
            #pragma unroll
            for (int j = 0; j < 8; ++j) { fh[j] = f2bf(scg[g]*ph[j]); fi[j] = f2bf(scg[g]*pi[j]); }
            Ahh[g][c] = fh; Aih[g][c] = fi;
        }
    short8 Aexp;
    #pragma unroll
    for (int j = 0; j < 8; ++j) {
        int k = quad*8 + j;
        Aexp[j] = (k < NKIN) ? f2bf(2.0f*LOG2E*W_e[(w*16 + m)*NKIN + k]) : (short)0;
    }
    short8 A1f[2][4];
    #pragma unroll
    for (int kc = 0; kc < 4; ++kc) {
        A1f[0][kc] = *(const short8*)(w1f + (size_t)(((w    )*4 + kc)*64 + lane)*8);
        A1f[1][kc] = *(const short8*)(w1f + (size_t)(((w + 8)*4 + kc)*64 + lane)*8);
    }
    f32x4 brz4, bzz4, bgn4, bin4, be4;
    #pragma unroll
    for (int r = 0; r < 4; ++r) {
        int h = hq + r;
        brz4[r] = -LOG2E*(bc_ih[h]      + bc_hh[h]);
        bzz4[r] =  LOG2E*(bc_ih[NH + h] + bc_hh[NH + h]);
        bgn4[r] = 2.0f*LOG2E*bc_hh[2*NH + h];
        bin4[r] = 2.0f*LOG2E*bc_ih[2*NH + h];
        be4[r]  = 2.0f*LOG2E*b_e[h];
    }

    // ================= in-kernel spline (Thomas, reversed elimination) =================
    const bool stg = (lane < 16);
    const int sb = w*2 + (lane >> 3), sk = lane & 7;
    const size_t scol = (size_t)(b0 + sb)*NKIN + sk;   // only valid for stg lanes
    float* cpS = (float*)E1;
    float prex_last = 0.f;
    if (stg) prex_last = pre_x[(size_t)(NTP-1)*BKIN + scol];
    if (stg) {
        const float r6 = 6.0f/(0.1f*0.1f);
        float c = 0.f, d = 0.f;
        float yp = fx[(size_t)127*BKIN + scol];
        float y0 = fx[(size_t)126*BKIN + scol];
        float ym = fx[(size_t)125*BKIN + scol];
        #pragma unroll 4
        for (int j = 127; j >= 1; --j) {
            float r = r6*(ym - 2.f*y0 + yp);
            c = __builtin_amdgcn_rcpf(4.f - c);
            d = (r - d)*c;
            UM[(size_t)j*BKIN + scol] = d;
            if (tid == 0) cpS[128 - j] = c;
            yp = y0; y0 = ym;
            ym = (j >= 3) ? fx[(size_t)(j-3)*BKIN + scol] : prex_last;
        }
    }
    __syncthreads();   // FULL: same-thread global RAW on UM
    if (stg) {
        const float KK = 0.01f/16.0f;
        float Mp = 0.f;
        float y0 = prex_last;
        float y1 = fx[scol];
        #pragma unroll 4
        for (int j = 1; j <= 127; ++j) {
            float dj = UM[(size_t)j*BKIN + scol];
            float e  = cpS[128 - j];
            float Mj = dj - e*Mp;
            UM[(size_t)(j-1)*BKIN + scol] = 0.5f*(y0 + y1) - KK*(Mp + Mj);
            Mp = Mj; y0 = y1;
            y1 = fx[(size_t)j*BKIN + scol];
        }
        UM[(size_t)127*BKIN + scol] = 0.5f*(y0 + y1) - KK*Mp;
    }
    __syncthreads();   // FULL: UM writes drained; E1 free again

    // ================= RK4 prologue =================
    if (stg) {
        UMb[sb*40 + 8 + (lane & 3)] = 0;
        U1b[sb*40 + 8 + (lane & 3)] = 0;
        UMb[sb*40 + sk] = f2bf(prex_last);
    }
    BAR();
    {   // x0 = tanh-expand(u0_start) -> xmT
        short8 b = *(const short8*)(UMb + m*40 + quad*8);
        f32x4 c0 = be4;
        c0 = __builtin_amdgcn_mfma_f32_16x16x32_bf16(Aexp, b, c0, 0, 0, 0);
        f32x4 xv = tanh1(c0);
        st4(xmT + m*136 + hq, xv);
    }
    BAR();
    f32x4 gi0[3] = {z4, z4, bin4};
    gemmB(xmT + m*136 + quad*8, Aih, gi0);
    if (stg) { UMb[sb*40 + sk] = f2bf(UM[scol]); U1b[sb*40 + sk] = f2bf(fx[scol]); }
    BAR();
    {   // expand u(0) -> xmT, x1T
        short8 bm = *(const short8*)(UMb + m*40 + quad*8);
        short8 b1 = *(const short8*)(U1b + m*40 + quad*8);
        f32x4 cm = be4, c1 = be4;
        cm = __builtin_amdgcn_mfma_f32_16x16x32_bf16(Aexp, bm, cm, 0, 0, 0);
        c1 = __builtin_amdgcn_mfma_f32_16x16x32_bf16(Aexp, b1, c1, 0, 0, 0);
        f32x4 xm, x1;
        tanh2(cm, c1, xm, x1);
        st4(xmT + m*136 + hq, xm);
        st4(x1T + m*136 + hq, x1);
    }
    float fxv = 0.f, umv = 0.f;
    if (stg) { fxv = fx[(size_t)BKIN + scol]; umv = UM[(size_t)BKIN + scol]; }  // u(1)
    BAR();
    // gim for st=0 computed here; gi1 is computed in-loop (P2) from x1T.
    f32x4 gim[3] = {z4, z4, bin4}, gi1[3] = {z4, z4, bin4};
    gemmB(xmT + m*136 + quad*8, Aih, gim);

    // ================= RK4 loop: 4 fast barriers/step =================
    // P1 = k1 + head1(st-1) | P2 = k2 + gi1 + stage2(st-1) + staging u(st+1)
    // P3 = k3 + expand(st+1) | P4 = k4 + y-upd + gim(st+1) + prefetch u(st+2)
    // MFMA balance {20,25,14,24} (was {20,13,14,36}): gi1's gemm moved from
    // P4(st) to P2(st+1) -- legal since x1T written P3(st), overwritten
    // P3(st+1), first use P4(st+1); gives P2 an independent MFMA chain.
    for (int st = 0; st < NL; ++st) {
        // ---- P1: k1 + head1(st-1) (shared yTa read) ----
        short8 byf[4];
        ld4(yTa + m*136 + quad*8, byf);
        f32x4 gh[3] = {brz4, bzz4, bgn4};
        gemmR(byf, Ahh, gh);
        if (st > 0) {
            f32x4 o0 = z4, o1 = z4;
            #pragma unroll
            for (int kc = 0; kc < 4; ++kc) {
                o0 = __builtin_amdgcn_mfma_f32_16x16x32_bf16(A1f[0][kc], byf[kc], o0, 0, 0, 0);
                o1 = __builtin_amdgcn_mfma_f32_16x16x32_bf16(A1f[1][kc], byf[kc], o1, 0, 0, 0);
            }
            f32x4 t0, t1;
            tanh2(o0, o1, t0, t1);
            st4(oT + m*264 + w*16     + quad*4, t0);
            st4(oT + m*264 + (w+8)*16 + quad*4, t1);
        }
        f32x4 K, Ks, ye;
        gateK(gi0, gh, y, K);
        Ks = K; ye = y + 0.5f*K;
        st4(yTb + m*136 + hq, ye);
        BAR();                                                  // B1
        // ---- P2: k2 + gi1(st) + stage2(st-1) + staging u(st+1) ----
        if (stg) { UMb[sb*40 + sk] = f2bf(umv); U1b[sb*40 + sk] = f2bf(fxv); }
        gh[0] = brz4; gh[1] = bzz4; gh[2] = bgn4;
        gemmB(yTb + m*136 + quad*8, Ahh, gh);
        gi1[0] = z4; gi1[1] = z4; gi1[2] = bin4;
        gemmB(x1T + m*136 + quad*8, Aih, gi1);      // x1T still holds u(st) endpoint
        if (st > 0 && w == ((st-1) & 7)) {
            f32x4 oc = z4;
            #pragma unroll
            for (int kc = 0; kc < 8; ++kc) {
                short8 a2 = *(const short8*)(w2S + (kc*64 + lane)*8);
                short8 b  = *(const short8*)(oT + m*264 + kc*32 + quad*8);
                oc = __builtin_amdgcn_mfma_f32_16x16x32_bf16(a2, b, oc, 0, 0, 0);
            }
            if (quad == 0)
                *(f32x4*)(out + ((size_t)(st-1)*NB + b0 + m)*NKOUT) = oc;
        }
        gateK(gim, gh, ye, K);
        Ks += 2.0f*K; ye = y + 0.5f*K;
        st4(E1 + m*136 + hq, ye);
        BAR();                                                  // B2
        // ---- P3: k3 + expand(st+1) ----
        gh[0] = brz4; gh[1] = bzz4; gh[2] = bgn4;
        gemmB(E1 + m*136 + quad*8, Ahh, gh);
        {
            short8 bm = *(const short8*)(UMb + m*40 + quad*8);
            short8 b1 = *(const short8*)(U1b + m*40 + quad*8);
            f32x4 cm = be4, c1 = be4;
            cm = __builtin_amdgcn_mfma_f32_16x16x32_bf16(Aexp, bm, cm, 0, 0, 0);
            c1 = __builtin_amdgcn_mfma_f32_16x16x32_bf16(Aexp, b1, c1, 0, 0, 0);
            f32x4 xm, x1;
            tanh2(cm, c1, xm, x1);
            st4(xmT + m*136 + hq, xm);
            st4(x1T + m*136 + hq, x1);
        }
        gateK(gim, gh, ye, K);
        Ks += 2.0f*K; ye = y + K;
        st4(yTb + m*136 + hq, ye);
        BAR();                                                  // B3
        // ---- P4: k4 + y update + gim(st+1) + prefetch u(st+2) ----
        if (stg) {
            int sn = (st + 2 < NL) ? st + 2 : NL - 1;
            fxv = fx[(size_t)sn*BKIN + scol];
            umv = UM[(size_t)sn*BKIN + scol];
        }
        gh[0] = brz4; gh[1] = bzz4; gh[2] = bgn4;
        gemmB(yTb + m*136 + quad*8, Ahh, gh);
        gateK(gi1, gh, ye, K);
        y += (1.0f/6.0f)*(Ks + K);
        st4(yTa + m*136 + hq, y);
        gi0[0] = gi1[0]; gi0[1] = gi1[1]; gi0[2] = gi1[2];
        gim[0] = z4; gim[1] = z4; gim[2] = bin4;
        gemmB(xmT + m*136 + quad*8, Aih, gim);
        BAR();                                                  // B4
    }

    // ================= epilogue: head + stage2 for out[127] =================
    {
        short8 byf[4];
        ld4(yTa + m*136 + quad*8, byf);
        f32x4 o0 = z4, o1 = z4;
        #pragma unroll
        for (int kc = 0; kc < 4; ++kc) {
            o0 = __builtin_amdgcn_mfma_f32_16x16x32_bf16(A1f[0][kc], byf[kc], o0, 0, 0, 0);
            o1 = __builtin_amdgcn_mfma_f32_16x16x32_bf16(A1f[1][kc], byf[kc], o1, 0, 0, 0);
        }
        f32x4 t0, t1;
        tanh2(o0, o1, t0, t1);
        st4(oT + m*264 + w*16     + quad*4, t0);
        st4(oT + m*264 + (w+8)*16 + quad*4, t1);
        BAR();
        if (w == 7) {
            f32x4 oc = z4;
            #pragma unroll
            for (int kc = 0; kc < 8; ++kc) {
                short8 a2 = *(const short8*)(w2S + (kc*64 + lane)*8);
                short8 b  = *(const short8*)(oT + m*264 + kc*32 + quad*8);
                oc = __builtin_amdgcn_mfma_f32_16x16x32_bf16(a2, b, oc, 0, 0, 0);
            }
            if (quad == 0)
                *(f32x4*)(out + ((size_t)(NL-1)*NB + b0 + m)*NKOUT) = oc;
        }
    }
}

extern "C" void kernel_launch(void* const* d_in, const int* in_sizes, int n_in,
                              void* d_out, int out_size, void* d_ws, size_t ws_size,
                              hipStream_t stream)
{
    const float* pre_x = (const float*)d_in[0];
    const float* pre_y = (const float*)d_in[1];
    const float* fx    = (const float*)d_in[2];
    const float* W_ih  = (const float*)d_in[3];
    const float* W_hh  = (const float*)d_in[4];
    const float* b_ih  = (const float*)d_in[5];
    const float* b_hh  = (const float*)d_in[6];
    const float* W_e   = (const float*)d_in[7];
    const float* b_e   = (const float*)d_in[8];
    const float* Wc_ih = (const float*)d_in[9];
    const float* Wc_hh = (const float*)d_in[10];
    const float* bc_ih = (const float*)d_in[11];
    const float* bc_hh = (const float*)d_in[12];
    const float* W1    = (const float*)d_in[13];
    const float* W2    = (const float*)d_in[14];
    float* out = (float*)d_out;

    float* UM  = (float*)d_ws;                                  // 128*4096*8 fp32 = 16.78 MB
    short* w1f = (short*)((char*)d_ws + (size_t)NL*NB*NKIN*4);  // 32768 shorts
    short* w2f = w1f + 16*4*64*8;                               // 4096 shorts

    prep_frags<<<dim3(8), dim3(256), 0, stream>>>(W1, W2, w1f, w2f);
    fused_kernel<<<dim3(NB/16), dim3(512), 0, stream>>>(
        pre_x, pre_y, fx, W_ih, W_hh, b_ih, b_hh, W_e, b_e,
        Wc_ih, Wc_hh, bc_ih, bc_hh, UM, w1f, w2f, out);
}